// Round 9
// baseline (1064.973 us; speedup 1.0000x reference)
//
#include <hip/hip_runtime.h>

// ---------------------------------------------------------------------------
// GDN attention block, MI355X (gfx950).
//   scan: WY/chunked gated delta rule, C=16. Per chunk: KK/KQ/S[K|Q]^T via
//   MFMA; A,M built with exp2 log-gate ratios (f32); 16-step forward
//   substitution (1 wave, f32); O = U M^T + diag(gamma) SWq via MFMA;
//   S <- gEnd*S + Uds^T K via MFMA. S master f32, MFMA inputs bf16.
//   1 block (4 waves) per (b,h), 256 chunks sequential.
// Rest of pipeline unchanged (bf16 MFMA GEMMs, fused prep, rmsnorm, Wo).
// ---------------------------------------------------------------------------

typedef __attribute__((ext_vector_type(8))) short short8;
typedef __attribute__((ext_vector_type(4))) float f32x4;

#define B_ 2
#define S_ 4096
#define D_ 1024
#define H_ 16
#define R_ 48
#define M_ 8192  // B*S
#define CW 16
#define NCH (S_ / CW)

__device__ __forceinline__ unsigned short f2bf(float f) {
  unsigned u = __float_as_uint(f);
  u += 0x7FFFu + ((u >> 16) & 1u);
  return (unsigned short)(u >> 16);
}
__device__ __forceinline__ float bf2f(unsigned short u) {
  return __uint_as_float(((unsigned)u) << 16);
}

#define GLDS16(g, l) __builtin_amdgcn_global_load_lds(                        \
    (const __attribute__((address_space(1))) unsigned int*)(g),              \
    (__attribute__((address_space(3))) unsigned int*)(l), 16, 0, 0)

// --------------------------------------------------------------- cast x->bf16
__global__ __launch_bounds__(256) void cast_bf16_kernel(
    const float* __restrict__ in, unsigned short* __restrict__ out, int n4) {
  int i = blockIdx.x * 256 + threadIdx.x;
  for (; i < n4; i += gridDim.x * 256) {
    float4 v = ((const float4*)in)[i];
    ushort4 o;
    o.x = f2bf(v.x); o.y = f2bf(v.y); o.z = f2bf(v.z); o.w = f2bf(v.w);
    ((ushort4*)out)[i] = o;
  }
}

// ------------------------------------------------- W[K][N] -> Wt[N][K] (bf16)
__global__ void transpose_w_kernel(const float* __restrict__ W,
                                   unsigned short* __restrict__ Wt,
                                   int Kd, int N) {
  __shared__ float tile[32][33];
  int n0 = blockIdx.x * 32, k0 = blockIdx.y * 32;
  int tx = threadIdx.x, ty = threadIdx.y;  // 32 x 8
#pragma unroll
  for (int i = 0; i < 32; i += 8)
    tile[ty + i][tx] = W[(size_t)(k0 + ty + i) * N + n0 + tx];
  __syncthreads();
#pragma unroll
  for (int i = 0; i < 32; i += 8)
    Wt[(size_t)(n0 + ty + i) * Kd + k0 + tx] = f2bf(tile[tx][ty + i]);
}

// -------------------------------------- pack [Wf|Wl] -> wfl[32][1024] bf16
__global__ __launch_bounds__(256) void pack_wfl_kernel(
    const float* __restrict__ Wf, const float* __restrict__ Wl,
    unsigned short* __restrict__ wfl) {
  int o = blockIdx.x * 256 + threadIdx.x;  // 32768 total
  int j = o >> 10, k = o & 1023;
  float v = (j < 16) ? Wf[k * 16 + j] : Wl[k * 16 + (j - 16)];
  wfl[o] = f2bf(v);
}

// ------------------------------------------------------------- bf16 MFMA GEMM
template <bool BF16OUT>
__global__ __launch_bounds__(256) void gemm_bt_kernel(
    const unsigned short* __restrict__ A, const unsigned short* __restrict__ Bt,
    void* __restrict__ Cv, int M, int N, int Kd) {
  __shared__ alignas(16) unsigned short lds[2 * 128 * 64];  // 32 KiB
  unsigned short* ldsA = lds;
  unsigned short* ldsB = lds + 128 * 64;
  int tid = threadIdx.x;
  int wave = tid >> 6, lane = tid & 63;
  int nBlocks = N >> 7;
  int bm = blockIdx.x / nBlocks, bn = blockIdx.x % nBlocks;
  int m0 = bm << 7, n0 = bn << 7;
  int wm = (wave >> 1) << 6, wn = (wave & 1) << 6;

  f32x4 acc[4][4] = {};

  int rowInChunk = lane >> 3;
  int kOff = (lane & 7) * 8;

  const unsigned short* Abase = A + (size_t)m0 * Kd;
  const unsigned short* Bbase = Bt + (size_t)n0 * Kd;

  for (int k0 = 0; k0 < Kd; k0 += 64) {
    __syncthreads();
#pragma unroll
    for (int r = 0; r < 4; r++) {
      int c = wave * 4 + r;
      int row = c * 8 + rowInChunk;
      GLDS16(Abase + (size_t)row * Kd + k0 + kOff, ldsA + c * 512);
    }
#pragma unroll
    for (int r = 0; r < 4; r++) {
      int c = wave * 4 + r;
      int row = c * 8 + rowInChunk;
      GLDS16(Bbase + (size_t)row * Kd + k0 + kOff, ldsB + c * 512);
    }
    asm volatile("s_waitcnt vmcnt(0)" ::: "memory");
    __syncthreads();
#pragma unroll
    for (int kk = 0; kk < 2; kk++) {
      short8 af[4], bfr[4];
      int kb = kk * 32 + (lane >> 4) * 8;
#pragma unroll
      for (int i = 0; i < 4; i++) {
        int ar = wm + i * 16 + (lane & 15);
        af[i] = *(const short8*)(ldsA + ar * 64 + kb);
        int br = wn + i * 16 + (lane & 15);
        bfr[i] = *(const short8*)(ldsB + br * 64 + kb);
      }
#pragma unroll
      for (int i = 0; i < 4; i++)
#pragma unroll
        for (int j = 0; j < 4; j++)
          acc[i][j] = __builtin_amdgcn_mfma_f32_16x16x32_bf16(
              af[i], bfr[j], acc[i][j], 0, 0, 0);
    }
  }
  int cr = (lane >> 4) * 4;
  int cc = lane & 15;
#pragma unroll
  for (int i = 0; i < 4; i++)
#pragma unroll
    for (int j = 0; j < 4; j++)
#pragma unroll
      for (int rg = 0; rg < 4; rg++) {
        int row = m0 + wm + i * 16 + cr + rg;
        int col = n0 + wn + j * 16 + cc;
        if (BF16OUT)
          ((unsigned short*)Cv)[(size_t)row * N + col] = f2bf(acc[i][j][rg]);
        else
          ((float*)Cv)[(size_t)row * N + col] = acc[i][j][rg];
      }
}

// ---------------------------- alpha/beta via MFMA: [8192x1024]@[32x1024]^T
__global__ __launch_bounds__(256) void fl_gemm_kernel(
    const unsigned short* __restrict__ xb, const unsigned short* __restrict__ wfl,
    const float* __restrict__ bfv, const float* __restrict__ blv,
    float* __restrict__ alpha, float* __restrict__ beta) {
  __shared__ alignas(16) unsigned short ldsA[128 * 64];
  __shared__ alignas(16) unsigned short ldsB[32 * 64];
  int tid = threadIdx.x, wave = tid >> 6, lane = tid & 63;
  int m0 = blockIdx.x << 7;
  f32x4 acc[2][2] = {};
  int rowInChunk = lane >> 3, kOff = (lane & 7) * 8;
  const unsigned short* Abase = xb + (size_t)m0 * 1024;

  for (int k0 = 0; k0 < 1024; k0 += 64) {
    __syncthreads();
#pragma unroll
    for (int r = 0; r < 4; r++) {
      int ch = wave * 4 + r;
      int row = ch * 8 + rowInChunk;
      GLDS16(Abase + (size_t)row * 1024 + k0 + kOff, ldsA + ch * 512);
    }
    {
      int row = wave * 8 + rowInChunk;
      GLDS16(wfl + (size_t)row * 1024 + k0 + kOff, ldsB + wave * 512);
    }
    asm volatile("s_waitcnt vmcnt(0)" ::: "memory");
    __syncthreads();
#pragma unroll
    for (int kk = 0; kk < 2; kk++) {
      int kb2 = kk * 32 + (lane >> 4) * 8;
      short8 af[2], bfr[2];
#pragma unroll
      for (int i = 0; i < 2; i++)
        af[i] = *(const short8*)(ldsA + (wave * 32 + i * 16 + (lane & 15)) * 64 + kb2);
#pragma unroll
      for (int j = 0; j < 2; j++)
        bfr[j] = *(const short8*)(ldsB + (j * 16 + (lane & 15)) * 64 + kb2);
#pragma unroll
      for (int i = 0; i < 2; i++)
#pragma unroll
        for (int j = 0; j < 2; j++)
          acc[i][j] = __builtin_amdgcn_mfma_f32_16x16x32_bf16(
              af[i], bfr[j], acc[i][j], 0, 0, 0);
    }
  }
  int cr = (lane >> 4) * 4, cc = lane & 15;
#pragma unroll
  for (int i = 0; i < 2; i++)
#pragma unroll
    for (int j = 0; j < 2; j++)
#pragma unroll
      for (int rg = 0; rg < 4; rg++) {
        int row = m0 + wave * 32 + i * 16 + cr + rg;
        int col = j * 16 + cc;
        float z = acc[i][j][rg] + ((col < 16) ? bfv[col] : blv[col - 16]);
        float s = 1.f / (1.f + __expf(-z));
        int bb = row >> 12, tt = row & 4095, hh = col & 15;
        float* dst = (col < 16) ? alpha : beta;
        dst[((size_t)(bb * 16 + hh)) * 4096 + tt] = s;
      }
}

// ------------------------ conv + rmsnorm + low-rank mix + k-tilde normalize
__global__ __launch_bounds__(256) void prep_kernel(
    const unsigned short* __restrict__ xqkv, const unsigned short* __restrict__ rqk,
    const float* __restrict__ cq, const float* __restrict__ ck,
    const float* __restrict__ cv, const float* __restrict__ gs,
    const float* __restrict__ qnw, const float* __restrict__ knw,
    unsigned short* __restrict__ qt, unsigned short* __restrict__ kt,
    unsigned short* __restrict__ vc) {
  int m = blockIdx.x;
  int b = m >> 12, t = m & 4095;
  int tid = threadIdx.x;
  int c4 = tid << 2;
  int h = c4 >> 6;
  int j4 = c4 & 63;

  float wq[4][4], wk[4][4], wv[4][4];
#pragma unroll
  for (int u = 0; u < 4; u++) {
    *(float4*)wq[u] = *(const float4*)(cq + (c4 + u) * 4);
    *(float4*)wk[u] = *(const float4*)(ck + (c4 + u) * 4);
    *(float4*)wv[u] = *(const float4*)(cv + (c4 + u) * 4);
  }
  float qv[4] = {0, 0, 0, 0}, kv[4] = {0, 0, 0, 0}, vv[4] = {0, 0, 0, 0};
#pragma unroll
  for (int j = 0; j < 4; j++) {
    int tt = t + j - 3;
    if (tt < 0) continue;
    const unsigned short* xr = xqkv + ((size_t)((b << 12) + tt)) * 3072;
    ushort4 uq = *(const ushort4*)(xr + c4);
    ushort4 uk = *(const ushort4*)(xr + 1024 + c4);
    ushort4 uv = *(const ushort4*)(xr + 2048 + c4);
    float xq[4] = {bf2f(uq.x), bf2f(uq.y), bf2f(uq.z), bf2f(uq.w)};
    float xk[4] = {bf2f(uk.x), bf2f(uk.y), bf2f(uk.z), bf2f(uk.w)};
    float xv[4] = {bf2f(uv.x), bf2f(uv.y), bf2f(uv.z), bf2f(uv.w)};
#pragma unroll
    for (int u = 0; u < 4; u++) {
      qv[u] = fmaf(wq[u][j], xq[u], qv[u]);
      kv[u] = fmaf(wk[u][j], xk[u], kv[u]);
      vv[u] = fmaf(wv[u][j], xv[u], vv[u]);
    }
  }
  float ssq = qv[0] * qv[0] + qv[1] * qv[1] + qv[2] * qv[2] + qv[3] * qv[3];
  ssq += __shfl_xor(ssq, 1); ssq += __shfl_xor(ssq, 2);
  ssq += __shfl_xor(ssq, 4); ssq += __shfl_xor(ssq, 8);
  float qsc = rsqrtf(ssq * (1.f / 64.f) + 1e-6f);
  float ssk = kv[0] * kv[0] + kv[1] * kv[1] + kv[2] * kv[2] + kv[3] * kv[3];
  ssk += __shfl_xor(ssk, 1); ssk += __shfl_xor(ssk, 2);
  ssk += __shfl_xor(ssk, 4); ssk += __shfl_xor(ssk, 8);
  float ksc = rsqrtf(ssk * (1.f / 64.f) + 1e-6f);

  float lam = fabsf(gs[h]);
  float rq[4] = {0, 0, 0, 0}, rk[4] = {0, 0, 0, 0};
  if (j4 < R_) {
    const unsigned short* rr = rqk + (size_t)m * 1536;
    ushort4 uq = *(const ushort4*)(rr + h * R_ + j4);
    ushort4 uk = *(const ushort4*)(rr + 768 + h * R_ + j4);
    rq[0] = bf2f(uq.x); rq[1] = bf2f(uq.y); rq[2] = bf2f(uq.z); rq[3] = bf2f(uq.w);
    rk[0] = bf2f(uk.x); rk[1] = bf2f(uk.y); rk[2] = bf2f(uk.z); rk[3] = bf2f(uk.w);
  }
  float qtv[4], ksum[4];
#pragma unroll
  for (int u = 0; u < 4; u++) {
    float qn = qv[u] * qsc * qnw[j4 + u];
    float kn = kv[u] * ksc * knw[j4 + u];
    qtv[u] = fmaf(lam, rq[u], qn);
    ksum[u] = fmaf(lam, rk[u], kn);
  }
  float ss2 = ksum[0] * ksum[0] + ksum[1] * ksum[1] + ksum[2] * ksum[2] +
              ksum[3] * ksum[3];
  ss2 += __shfl_xor(ss2, 1); ss2 += __shfl_xor(ss2, 2);
  ss2 += __shfl_xor(ss2, 4); ss2 += __shfl_xor(ss2, 8);
  float inv = 1.f / fmaxf(sqrtf(ss2), 1e-12f);

  size_t ob = ((size_t)((b * 16 + h) * 4096 + t)) * 64 + j4;
  ushort4 oq, ok, ov;
  oq.x = f2bf(qtv[0]); oq.y = f2bf(qtv[1]); oq.z = f2bf(qtv[2]); oq.w = f2bf(qtv[3]);
  ok.x = f2bf(ksum[0] * inv); ok.y = f2bf(ksum[1] * inv);
  ok.z = f2bf(ksum[2] * inv); ok.w = f2bf(ksum[3] * inv);
  ov.x = f2bf(vv[0]); ov.y = f2bf(vv[1]); ov.z = f2bf(vv[2]); ov.w = f2bf(vv[3]);
  *(ushort4*)(qt + ob) = oq;
  *(ushort4*)(kt + ob) = ok;
  *(ushort4*)(vc + ob) = ov;
}

// ------------------------------------------- WY chunked gated delta scan
// 1 block (4 waves) per (b,h); 256 chunks of CW=16 steps.
__global__ __launch_bounds__(256, 1) void scan_wy_kernel(
    const unsigned short* __restrict__ qt, const unsigned short* __restrict__ kt,
    const unsigned short* __restrict__ vc, const float* __restrict__ al,
    const float* __restrict__ be, float* __restrict__ attn) {
  __shared__ float Sf[64][65];                      // state f32
  __shared__ alignas(16) unsigned short Sb[64][72]; // state bf16
  __shared__ alignas(16) unsigned short Kc[2][32][72];  // rows 16..31 zero
  __shared__ alignas(16) unsigned short Qc[2][16][72];
  __shared__ alignas(16) unsigned short Vc[2][16][72];
  __shared__ float KK[16][17];
  __shared__ float KQ[16][17];
  __shared__ alignas(16) float Af[16][20];
  __shared__ alignas(16) unsigned short Mb[16][72]; // cols 16..31 zero
  __shared__ float SWk[64][17];
  __shared__ float SWq[64][17];
  __shared__ float C0[64][17];
  __shared__ unsigned short Ub[32][72];  // rows 16..31 zero
  __shared__ unsigned short Ud[32][72];  // rows 16..31 zero
  __shared__ float ga[2][16], gbx[2][16];
  __shared__ float gb_s[16], bg_s[16], ginv_s[16], gamt_s[16], gpow_s[16];

  int bh = blockIdx.x;
  int b = bh >> 4, h = bh & 15;
  int tid = threadIdx.x;
  int w = tid >> 6, l = tid & 63;

  const unsigned short* kb = kt + (size_t)bh * S_ * 64;
  const unsigned short* qb = qt + (size_t)bh * S_ * 64;
  const unsigned short* vb = vc + (size_t)bh * S_ * 64;
  const float* ap = al + (size_t)bh * S_;
  const float* bp = be + (size_t)bh * S_;
  float* ob = attn + (size_t)(b * S_) * 1024 + h * 64;

  // ---- zero-init LDS state + permanently-zero pads ----
  for (int i = tid; i < 64 * 65; i += 256) ((float*)Sf)[i] = 0.f;
  for (int i = tid; i < 64 * 72; i += 256) ((unsigned short*)Sb)[i] = 0;
  for (int i = tid; i < 2 * 32 * 72; i += 256) ((unsigned short*)Kc)[i] = 0;
  for (int i = tid; i < 16 * 72; i += 256) ((unsigned short*)Mb)[i] = 0;
  for (int i = tid; i < 32 * 72; i += 256) {
    ((unsigned short*)Ub)[i] = 0;
    ((unsigned short*)Ud)[i] = 0;
  }

  // ---- prefetch chunk 0 ----
  int srow = tid >> 4, sc4 = (tid & 15) * 4;
  ushort4 pk = *(const ushort4*)(kb + (size_t)srow * 64 + sc4);
  ushort4 pq = *(const ushort4*)(qb + (size_t)srow * 64 + sc4);
  ushort4 pv = *(const ushort4*)(vb + (size_t)srow * 64 + sc4);
  float pg = 0.f;
  if (tid < 16) pg = ap[tid];
  else if (tid < 32) pg = bp[tid - 16];

  __syncthreads();  // init done

  for (int cch = 0; cch < NCH; ++cch) {
    int p = cch & 1;
    int tg0 = cch * CW;
    // ---- staging: regs -> LDS buf p ----
    *(ushort4*)&Kc[p][srow][sc4] = pk;
    *(ushort4*)&Qc[p][srow][sc4] = pq;
    *(ushort4*)&Vc[p][srow][sc4] = pv;
    if (tid < 16) ga[p][tid] = pg;
    else if (tid < 32) gbx[p][tid - 16] = pg;
    // prefetch next chunk
    if (cch + 1 < NCH) {
      size_t cb = (size_t)(tg0 + CW) * 64;
      pk = *(const ushort4*)(kb + cb + (size_t)srow * 64 + sc4);
      pq = *(const ushort4*)(qb + cb + (size_t)srow * 64 + sc4);
      pv = *(const ushort4*)(vb + cb + (size_t)srow * 64 + sc4);
      if (tid < 16) pg = ap[tg0 + CW + tid];
      else if (tid < 32) pg = bp[tg0 + CW + tid - 16];
    }
    __syncthreads();  // B2: chunk data + prev-chunk state ready

    if (w == 0) {
      // gate arrays
      if (l < 16) {
        float tot = 0.f, lgv = 0.f;
#pragma unroll
        for (int s = 0; s < 16; s++) {
          float la = __log2f(ga[p][s]);
          tot += la;
          if (s <= l) lgv += la;
        }
        float la_l = __log2f(ga[p][l]);
        float lgp = lgv - la_l;
        float bt = gbx[p][l];
        gb_s[l] = bt;
        bg_s[l] = bt * exp2f(lgp);
        ginv_s[l] = exp2f(-lgv);
        gamt_s[l] = exp2f(lgv);
        gpow_s[l] = exp2f(tot - lgv);
      }
    } else if (w == 1) {
      // KK[t][s] = k_t.k_s ; KQ[t][s] = q_t.k_s
      f32x4 aK = {0.f, 0.f, 0.f, 0.f}, aQ = {0.f, 0.f, 0.f, 0.f};
#pragma unroll
      for (int kk = 0; kk < 2; kk++) {
        int ko = kk * 32 + (l >> 4) * 8;
        short8 kf = *(const short8*)&Kc[p][l & 15][ko];
        short8 qf = *(const short8*)&Qc[p][l & 15][ko];
        aK = __builtin_amdgcn_mfma_f32_16x16x32_bf16(kf, kf, aK, 0, 0, 0);
        aQ = __builtin_amdgcn_mfma_f32_16x16x32_bf16(qf, kf, aQ, 0, 0, 0);
      }
#pragma unroll
      for (int r = 0; r < 4; r++) {
        int t = (l >> 4) * 4 + r;
        KK[t][l & 15] = aK[r];
        KQ[t][l & 15] = aQ[r];
      }
    } else {
      // SWk / SWq: [64_i x 16_t] = Sb @ (Kc|Qc)^T
      const unsigned short* Bsrc = (w == 2) ? &Kc[p][0][0] : &Qc[p][0][0];
      short8 bf0, bf1;
      {
        int ko0 = (l >> 4) * 8, ko1 = 32 + (l >> 4) * 8;
        bf0 = *(const short8*)(Bsrc + (size_t)(l & 15) * 72 + ko0);
        bf1 = *(const short8*)(Bsrc + (size_t)(l & 15) * 72 + ko1);
      }
#pragma unroll
      for (int tile = 0; tile < 4; tile++) {
        f32x4 acc = {0.f, 0.f, 0.f, 0.f};
        short8 s0 = *(const short8*)&Sb[tile * 16 + (l & 15)][(l >> 4) * 8];
        short8 s1 = *(const short8*)&Sb[tile * 16 + (l & 15)][32 + (l >> 4) * 8];
        acc = __builtin_amdgcn_mfma_f32_16x16x32_bf16(s0, bf0, acc, 0, 0, 0);
        acc = __builtin_amdgcn_mfma_f32_16x16x32_bf16(s1, bf1, acc, 0, 0, 0);
#pragma unroll
        for (int r = 0; r < 4; r++) {
          int i = tile * 16 + (l >> 4) * 4 + r;
          if (w == 2) SWk[i][l & 15] = acc[r];
          else SWq[i][l & 15] = acc[r];
        }
      }
    }
    __syncthreads();  // B3

    // ---- build A, M(bf16), C0 ----
    {
      int t = tid >> 4, s = tid & 15;
      float kkv = KK[t][s], kqv = KQ[t][s];
      Af[t][s] = (s < t) ? bg_s[t] * ginv_s[s] * kkv : 0.f;
      float mv = (s <= t) ? gamt_s[t] * ginv_s[s] * kqv : 0.f;
      Mb[t][s] = f2bf(mv);
      int i = tid & 63, tq = tid >> 6;
#pragma unroll
      for (int j = 0; j < 4; j++) {
        int tt = tq * 4 + j;
        C0[i][tt] = gb_s[tt] * bf2f(Vc[p][tt][i]) - bg_s[tt] * SWk[i][tt];
      }
    }
    __syncthreads();  // B4

    // ---- forward substitution (wave 0, lane = i) ----
    if (w == 0) {
      float u[16];
#pragma unroll
      for (int t = 0; t < 16; t++) {
        f32x4 a0 = *(const f32x4*)&Af[t][0];
        f32x4 a1 = *(const f32x4*)&Af[t][4];
        f32x4 a2 = *(const f32x4*)&Af[t][8];
        f32x4 a3 = *(const f32x4*)&Af[t][12];
        float x = C0[l][t];
#pragma unroll
        for (int s = 0; s < 16; s++) {
          if (s >= t) break;
          float av = (s < 4) ? a0[s] : (s < 8) ? a1[s - 4]
                      : (s < 12) ? a2[s - 8] : a3[s - 12];
          x = fmaf(-av, u[s], x);
        }
        u[t] = x;
        Ub[t][l] = f2bf(x);
        Ud[t][l] = f2bf(x * gpow_s[t]);
      }
    }
    __syncthreads();  // B5

    // ---- O = U M^T + diag(gamt) SWq  (wave w -> i-tile w) ----
    {
      f32x4 acc = {0.f, 0.f, 0.f, 0.f};
      short8 mf = *(const short8*)&Mb[l & 15][(l >> 4) * 8];
      short8 uf;
#pragma unroll
      for (int j = 0; j < 8; j++)
        uf[j] = (short)Ub[(l >> 4) * 8 + j][w * 16 + (l & 15)];
      acc = __builtin_amdgcn_mfma_f32_16x16x32_bf16(mf, uf, acc, 0, 0, 0);
      int icol = w * 16 + (l & 15);
#pragma unroll
      for (int r = 0; r < 4; r++) {
        int t = (l >> 4) * 4 + r;
        float o = acc[r] + gamt_s[t] * SWq[icol][t];
        ob[(size_t)(tg0 + t) * 1024 + icol] = o;
      }
    }
    // ---- S <- gEnd*S + Uds^T K  (wave w -> i-block w) ----
    {
      float gE = gamt_s[15];
      short8 uaf;
#pragma unroll
      for (int j = 0; j < 8; j++)
        uaf[j] = (short)Ud[(l >> 4) * 8 + j][16 * w + (l & 15)];
#pragma unroll
      for (int jt = 0; jt < 4; jt++) {
        short8 kbf;
#pragma unroll
        for (int j = 0; j < 8; j++)
          kbf[j] = (short)Kc[p][(l >> 4) * 8 + j][jt * 16 + (l & 15)];
        f32x4 ci;
#pragma unroll
        for (int r = 0; r < 4; r++)
          ci[r] = gE * Sf[16 * w + (l >> 4) * 4 + r][jt * 16 + (l & 15)];
        ci = __builtin_amdgcn_mfma_f32_16x16x32_bf16(uaf, kbf, ci, 0, 0, 0);
#pragma unroll
        for (int r = 0; r < 4; r++) {
          int ii = 16 * w + (l >> 4) * 4 + r;
          int jj = jt * 16 + (l & 15);
          Sf[ii][jj] = ci[r];
          Sb[ii][jj] = f2bf(ci[r]);
        }
      }
    }
  }
}

// ------------------------------------------------ output rmsnorm -> bf16 rows
__global__ __launch_bounds__(256) void rmsnorm_out_kernel(
    const float* __restrict__ attn, const float* __restrict__ onw,
    unsigned short* __restrict__ normed) {
  int m = blockIdx.x, tid = threadIdx.x;
  const float* row = attn + (size_t)m * 1024;
  float xv[4];
  *(float4*)xv = *(const float4*)(row + tid * 4);
  float ss = xv[0] * xv[0] + xv[1] * xv[1] + xv[2] * xv[2] + xv[3] * xv[3];
#pragma unroll
  for (int o = 1; o < 64; o <<= 1) ss += __shfl_xor(ss, o);
  __shared__ float wss[4];
  if ((tid & 63) == 0) wss[tid >> 6] = ss;
  __syncthreads();
  float tot = wss[0] + wss[1] + wss[2] + wss[3];
  float sc = rsqrtf(tot * (1.f / 1024.f) + 1e-6f);
  float wv[4];
  *(float4*)wv = *(const float4*)(onw + tid * 4);
  ushort4 o4;
  o4.x = f2bf(xv[0] * sc * wv[0]);
  o4.y = f2bf(xv[1] * sc * wv[1]);
  o4.z = f2bf(xv[2] * sc * wv[2]);
  o4.w = f2bf(xv[3] * sc * wv[3]);
  *(ushort4*)(normed + (size_t)m * 1024 + tid * 4) = o4;
}

// ---------------------------------------------------------------------------
extern "C" void kernel_launch(void* const* d_in, const int* in_sizes, int n_in,
                              void* d_out, int out_size, void* d_ws,
                              size_t ws_size, hipStream_t stream) {
  const float* x = (const float*)d_in[0];
  const float* Wq = (const float*)d_in[1];
  const float* Wk = (const float*)d_in[2];
  const float* Wv = (const float*)d_in[3];
  const float* Wo = (const float*)d_in[4];
  const float* conv_q = (const float*)d_in[5];
  const float* conv_k = (const float*)d_in[6];
  const float* conv_v = (const float*)d_in[7];
  const float* Wf = (const float*)d_in[8];
  const float* bfv = (const float*)d_in[9];
  const float* Wl = (const float*)d_in[10];
  const float* blv = (const float*)d_in[11];
  const float* gs = (const float*)d_in[14];
  const float* qn_w = (const float*)d_in[15];
  const float* kn_w = (const float*)d_in[16];
  const float* on_w = (const float*)d_in[17];

  char* ws = (char*)d_ws;
  size_t used = 0;
  auto alloc = [&](size_t bytes) -> void* {
    void* p = (void*)(ws + used);
    used += (bytes + 255) & ~(size_t)255;
    return p;
  };
  unsigned short* xb = (unsigned short*)alloc((size_t)M_ * D_ * 2);
  unsigned short* wqkv_t = (unsigned short*)alloc((size_t)3072 * 1024 * 2);
  unsigned short* wr_t = (unsigned short*)alloc((size_t)1536 * 1024 * 2);
  unsigned short* wo_t = (unsigned short*)alloc((size_t)1024 * 1024 * 2);
  unsigned short* wfl = (unsigned short*)alloc((size_t)32 * 1024 * 2);
  unsigned short* xqkv = (unsigned short*)alloc((size_t)M_ * 3072 * 2);
  unsigned short* rqk = (unsigned short*)alloc((size_t)M_ * 1536 * 2);
  unsigned short* qt = (unsigned short*)alloc((size_t)M_ * 1024 * 2);
  unsigned short* kt = (unsigned short*)alloc((size_t)M_ * 1024 * 2);
  unsigned short* vc = (unsigned short*)alloc((size_t)M_ * 1024 * 2);
  float* alpha = (float*)alloc((size_t)B_ * H_ * S_ * 4);
  float* beta = (float*)alloc((size_t)B_ * H_ * S_ * 4);
  float* attn = (float*)xqkv;    // alias (xqkv dead after prep)
  unsigned short* normed = rqk;  // alias (rqk dead after prep)

  if (used > ws_size) return;

  cast_bf16_kernel<<<2048, 256, 0, stream>>>(x, xb, M_ * D_ / 4);

  dim3 tb(32, 8);
  transpose_w_kernel<<<dim3(32, 32), tb, 0, stream>>>(Wq, wqkv_t, 1024, 1024);
  transpose_w_kernel<<<dim3(32, 32), tb, 0, stream>>>(
      Wk, wqkv_t + (size_t)1024 * 1024, 1024, 1024);
  transpose_w_kernel<<<dim3(32, 32), tb, 0, stream>>>(
      Wv, wqkv_t + (size_t)2048 * 1024, 1024, 1024);
  transpose_w_kernel<<<dim3(24, 32), tb, 0, stream>>>(
      (const float*)d_in[12], wr_t, 1024, 768);
  transpose_w_kernel<<<dim3(24, 32), tb, 0, stream>>>(
      (const float*)d_in[13], wr_t + (size_t)768 * 1024, 1024, 768);
  transpose_w_kernel<<<dim3(32, 32), tb, 0, stream>>>(Wo, wo_t, 1024, 1024);
  pack_wfl_kernel<<<128, 256, 0, stream>>>(Wf, Wl, wfl);

  gemm_bt_kernel<true><<<64 * 24, 256, 0, stream>>>(xb, wqkv_t, xqkv, M_, 3072, 1024);
  gemm_bt_kernel<true><<<64 * 12, 256, 0, stream>>>(xb, wr_t, rqk, M_, 1536, 1024);

  fl_gemm_kernel<<<64, 256, 0, stream>>>(xb, wfl, bfv, blv, alpha, beta);

  prep_kernel<<<M_, 256, 0, stream>>>(xqkv, rqk, conv_q, conv_k, conv_v, gs,
                                      qn_w, kn_w, qt, kt, vc);

  scan_wy_kernel<<<B_ * H_, 256, 0, stream>>>(qt, kt, vc, alpha, beta, attn);

  rmsnorm_out_kernel<<<M_, 256, 0, stream>>>(attn, on_w, normed);

  gemm_bt_kernel<false><<<64 * 8, 256, 0, stream>>>(normed, wo_t, (float*)d_out,
                                                    M_, 1024, 1024);
}

// Round 10
// 939.269 us; speedup vs baseline: 1.1338x; 1.1338x over previous
//
#include <hip/hip_runtime.h>

// ---------------------------------------------------------------------------
// GDN attention block, MI355X (gfx950).
//   scan: WY/chunked gated delta rule, C=16, 1 block (4 waves) per (b,h).
//   This rev: transposed LDS copies (Ut/Udt/Kt) so all MFMA fragments load
//   via ds_read_b128; S lives in registers (wave-owned 16x64, MFMA C layout);
//   DPP prefix-sum gates; solve reads C0/gpow into regs, writes u via b128.
// Rest of pipeline unchanged (bf16 MFMA GEMMs, fused prep, rmsnorm, Wo).
// ---------------------------------------------------------------------------

typedef __attribute__((ext_vector_type(8))) short short8;
typedef __attribute__((ext_vector_type(4))) float f32x4;

#define B_ 2
#define S_ 4096
#define D_ 1024
#define H_ 16
#define R_ 48
#define M_ 8192  // B*S
#define CW 16
#define NCH (S_ / CW)

__device__ __forceinline__ unsigned short f2bf(float f) {
  unsigned u = __float_as_uint(f);
  u += 0x7FFFu + ((u >> 16) & 1u);
  return (unsigned short)(u >> 16);
}
__device__ __forceinline__ float bf2f(unsigned short u) {
  return __uint_as_float(((unsigned)u) << 16);
}

template <int CTRL>
__device__ __forceinline__ float dppadd0(float x) {  // bound_ctrl: OOB -> 0
  return x + __int_as_float(__builtin_amdgcn_update_dpp(
                 0, __float_as_int(x), CTRL, 0xF, 0xF, true));
}

#define GLDS16(g, l) __builtin_amdgcn_global_load_lds(                        \
    (const __attribute__((address_space(1))) unsigned int*)(g),              \
    (__attribute__((address_space(3))) unsigned int*)(l), 16, 0, 0)

// --------------------------------------------------------------- cast x->bf16
__global__ __launch_bounds__(256) void cast_bf16_kernel(
    const float* __restrict__ in, unsigned short* __restrict__ out, int n4) {
  int i = blockIdx.x * 256 + threadIdx.x;
  for (; i < n4; i += gridDim.x * 256) {
    float4 v = ((const float4*)in)[i];
    ushort4 o;
    o.x = f2bf(v.x); o.y = f2bf(v.y); o.z = f2bf(v.z); o.w = f2bf(v.w);
    ((ushort4*)out)[i] = o;
  }
}

// ------------------------------------------------- W[K][N] -> Wt[N][K] (bf16)
__global__ void transpose_w_kernel(const float* __restrict__ W,
                                   unsigned short* __restrict__ Wt,
                                   int Kd, int N) {
  __shared__ float tile[32][33];
  int n0 = blockIdx.x * 32, k0 = blockIdx.y * 32;
  int tx = threadIdx.x, ty = threadIdx.y;  // 32 x 8
#pragma unroll
  for (int i = 0; i < 32; i += 8)
    tile[ty + i][tx] = W[(size_t)(k0 + ty + i) * N + n0 + tx];
  __syncthreads();
#pragma unroll
  for (int i = 0; i < 32; i += 8)
    Wt[(size_t)(n0 + ty + i) * Kd + k0 + tx] = f2bf(tile[tx][ty + i]);
}

// -------------------------------------- pack [Wf|Wl] -> wfl[32][1024] bf16
__global__ __launch_bounds__(256) void pack_wfl_kernel(
    const float* __restrict__ Wf, const float* __restrict__ Wl,
    unsigned short* __restrict__ wfl) {
  int o = blockIdx.x * 256 + threadIdx.x;  // 32768 total
  int j = o >> 10, k = o & 1023;
  float v = (j < 16) ? Wf[k * 16 + j] : Wl[k * 16 + (j - 16)];
  wfl[o] = f2bf(v);
}

// ------------------------------------------------------------- bf16 MFMA GEMM
template <bool BF16OUT>
__global__ __launch_bounds__(256) void gemm_bt_kernel(
    const unsigned short* __restrict__ A, const unsigned short* __restrict__ Bt,
    void* __restrict__ Cv, int M, int N, int Kd) {
  __shared__ alignas(16) unsigned short lds[2 * 128 * 64];  // 32 KiB
  unsigned short* ldsA = lds;
  unsigned short* ldsB = lds + 128 * 64;
  int tid = threadIdx.x;
  int wave = tid >> 6, lane = tid & 63;
  int nBlocks = N >> 7;
  int bm = blockIdx.x / nBlocks, bn = blockIdx.x % nBlocks;
  int m0 = bm << 7, n0 = bn << 7;
  int wm = (wave >> 1) << 6, wn = (wave & 1) << 6;

  f32x4 acc[4][4] = {};

  int rowInChunk = lane >> 3;
  int kOff = (lane & 7) * 8;

  const unsigned short* Abase = A + (size_t)m0 * Kd;
  const unsigned short* Bbase = Bt + (size_t)n0 * Kd;

  for (int k0 = 0; k0 < Kd; k0 += 64) {
    __syncthreads();
#pragma unroll
    for (int r = 0; r < 4; r++) {
      int c = wave * 4 + r;
      int row = c * 8 + rowInChunk;
      GLDS16(Abase + (size_t)row * Kd + k0 + kOff, ldsA + c * 512);
    }
#pragma unroll
    for (int r = 0; r < 4; r++) {
      int c = wave * 4 + r;
      int row = c * 8 + rowInChunk;
      GLDS16(Bbase + (size_t)row * Kd + k0 + kOff, ldsB + c * 512);
    }
    asm volatile("s_waitcnt vmcnt(0)" ::: "memory");
    __syncthreads();
#pragma unroll
    for (int kk = 0; kk < 2; kk++) {
      short8 af[4], bfr[4];
      int kb = kk * 32 + (lane >> 4) * 8;
#pragma unroll
      for (int i = 0; i < 4; i++) {
        int ar = wm + i * 16 + (lane & 15);
        af[i] = *(const short8*)(ldsA + ar * 64 + kb);
        int br = wn + i * 16 + (lane & 15);
        bfr[i] = *(const short8*)(ldsB + br * 64 + kb);
      }
#pragma unroll
      for (int i = 0; i < 4; i++)
#pragma unroll
        for (int j = 0; j < 4; j++)
          acc[i][j] = __builtin_amdgcn_mfma_f32_16x16x32_bf16(
              af[i], bfr[j], acc[i][j], 0, 0, 0);
    }
  }
  int cr = (lane >> 4) * 4;
  int cc = lane & 15;
#pragma unroll
  for (int i = 0; i < 4; i++)
#pragma unroll
    for (int j = 0; j < 4; j++)
#pragma unroll
      for (int rg = 0; rg < 4; rg++) {
        int row = m0 + wm + i * 16 + cr + rg;
        int col = n0 + wn + j * 16 + cc;
        if (BF16OUT)
          ((unsigned short*)Cv)[(size_t)row * N + col] = f2bf(acc[i][j][rg]);
        else
          ((float*)Cv)[(size_t)row * N + col] = acc[i][j][rg];
      }
}

// ---------------------------- alpha/beta via MFMA: [8192x1024]@[32x1024]^T
__global__ __launch_bounds__(256) void fl_gemm_kernel(
    const unsigned short* __restrict__ xb, const unsigned short* __restrict__ wfl,
    const float* __restrict__ bfv, const float* __restrict__ blv,
    float* __restrict__ alpha, float* __restrict__ beta) {
  __shared__ alignas(16) unsigned short ldsA[128 * 64];
  __shared__ alignas(16) unsigned short ldsB[32 * 64];
  int tid = threadIdx.x, wave = tid >> 6, lane = tid & 63;
  int m0 = blockIdx.x << 7;
  f32x4 acc[2][2] = {};
  int rowInChunk = lane >> 3, kOff = (lane & 7) * 8;
  const unsigned short* Abase = xb + (size_t)m0 * 1024;

  for (int k0 = 0; k0 < 1024; k0 += 64) {
    __syncthreads();
#pragma unroll
    for (int r = 0; r < 4; r++) {
      int ch = wave * 4 + r;
      int row = ch * 8 + rowInChunk;
      GLDS16(Abase + (size_t)row * 1024 + k0 + kOff, ldsA + ch * 512);
    }
    {
      int row = wave * 8 + rowInChunk;
      GLDS16(wfl + (size_t)row * 1024 + k0 + kOff, ldsB + wave * 512);
    }
    asm volatile("s_waitcnt vmcnt(0)" ::: "memory");
    __syncthreads();
#pragma unroll
    for (int kk = 0; kk < 2; kk++) {
      int kb2 = kk * 32 + (lane >> 4) * 8;
      short8 af[2], bfr[2];
#pragma unroll
      for (int i = 0; i < 2; i++)
        af[i] = *(const short8*)(ldsA + (wave * 32 + i * 16 + (lane & 15)) * 64 + kb2);
#pragma unroll
      for (int j = 0; j < 2; j++)
        bfr[j] = *(const short8*)(ldsB + (j * 16 + (lane & 15)) * 64 + kb2);
#pragma unroll
      for (int i = 0; i < 2; i++)
#pragma unroll
        for (int j = 0; j < 2; j++)
          acc[i][j] = __builtin_amdgcn_mfma_f32_16x16x32_bf16(
              af[i], bfr[j], acc[i][j], 0, 0, 0);
    }
  }
  int cr = (lane >> 4) * 4, cc = lane & 15;
#pragma unroll
  for (int i = 0; i < 2; i++)
#pragma unroll
    for (int j = 0; j < 2; j++)
#pragma unroll
      for (int rg = 0; rg < 4; rg++) {
        int row = m0 + wave * 32 + i * 16 + cr + rg;
        int col = j * 16 + cc;
        float z = acc[i][j][rg] + ((col < 16) ? bfv[col] : blv[col - 16]);
        float s = 1.f / (1.f + __expf(-z));
        int bb = row >> 12, tt = row & 4095, hh = col & 15;
        float* dst = (col < 16) ? alpha : beta;
        dst[((size_t)(bb * 16 + hh)) * 4096 + tt] = s;
      }
}

// ------------------------ conv + rmsnorm + low-rank mix + k-tilde normalize
__global__ __launch_bounds__(256) void prep_kernel(
    const unsigned short* __restrict__ xqkv, const unsigned short* __restrict__ rqk,
    const float* __restrict__ cq, const float* __restrict__ ck,
    const float* __restrict__ cv, const float* __restrict__ gs,
    const float* __restrict__ qnw, const float* __restrict__ knw,
    unsigned short* __restrict__ qt, unsigned short* __restrict__ kt,
    unsigned short* __restrict__ vc) {
  int m = blockIdx.x;
  int b = m >> 12, t = m & 4095;
  int tid = threadIdx.x;
  int c4 = tid << 2;
  int h = c4 >> 6;
  int j4 = c4 & 63;

  float wq[4][4], wk[4][4], wv[4][4];
#pragma unroll
  for (int u = 0; u < 4; u++) {
    *(float4*)wq[u] = *(const float4*)(cq + (c4 + u) * 4);
    *(float4*)wk[u] = *(const float4*)(ck + (c4 + u) * 4);
    *(float4*)wv[u] = *(const float4*)(cv + (c4 + u) * 4);
  }
  float qv[4] = {0, 0, 0, 0}, kv[4] = {0, 0, 0, 0}, vv[4] = {0, 0, 0, 0};
#pragma unroll
  for (int j = 0; j < 4; j++) {
    int tt = t + j - 3;
    if (tt < 0) continue;
    const unsigned short* xr = xqkv + ((size_t)((b << 12) + tt)) * 3072;
    ushort4 uq = *(const ushort4*)(xr + c4);
    ushort4 uk = *(const ushort4*)(xr + 1024 + c4);
    ushort4 uv = *(const ushort4*)(xr + 2048 + c4);
    float xq[4] = {bf2f(uq.x), bf2f(uq.y), bf2f(uq.z), bf2f(uq.w)};
    float xk[4] = {bf2f(uk.x), bf2f(uk.y), bf2f(uk.z), bf2f(uk.w)};
    float xv[4] = {bf2f(uv.x), bf2f(uv.y), bf2f(uv.z), bf2f(uv.w)};
#pragma unroll
    for (int u = 0; u < 4; u++) {
      qv[u] = fmaf(wq[u][j], xq[u], qv[u]);
      kv[u] = fmaf(wk[u][j], xk[u], kv[u]);
      vv[u] = fmaf(wv[u][j], xv[u], vv[u]);
    }
  }
  float ssq = qv[0] * qv[0] + qv[1] * qv[1] + qv[2] * qv[2] + qv[3] * qv[3];
  ssq += __shfl_xor(ssq, 1); ssq += __shfl_xor(ssq, 2);
  ssq += __shfl_xor(ssq, 4); ssq += __shfl_xor(ssq, 8);
  float qsc = rsqrtf(ssq * (1.f / 64.f) + 1e-6f);
  float ssk = kv[0] * kv[0] + kv[1] * kv[1] + kv[2] * kv[2] + kv[3] * kv[3];
  ssk += __shfl_xor(ssk, 1); ssk += __shfl_xor(ssk, 2);
  ssk += __shfl_xor(ssk, 4); ssk += __shfl_xor(ssk, 8);
  float ksc = rsqrtf(ssk * (1.f / 64.f) + 1e-6f);

  float lam = fabsf(gs[h]);
  float rq[4] = {0, 0, 0, 0}, rk[4] = {0, 0, 0, 0};
  if (j4 < R_) {
    const unsigned short* rr = rqk + (size_t)m * 1536;
    ushort4 uq = *(const ushort4*)(rr + h * R_ + j4);
    ushort4 uk = *(const ushort4*)(rr + 768 + h * R_ + j4);
    rq[0] = bf2f(uq.x); rq[1] = bf2f(uq.y); rq[2] = bf2f(uq.z); rq[3] = bf2f(uq.w);
    rk[0] = bf2f(uk.x); rk[1] = bf2f(uk.y); rk[2] = bf2f(uk.z); rk[3] = bf2f(uk.w);
  }
  float qtv[4], ksum[4];
#pragma unroll
  for (int u = 0; u < 4; u++) {
    float qn = qv[u] * qsc * qnw[j4 + u];
    float kn = kv[u] * ksc * knw[j4 + u];
    qtv[u] = fmaf(lam, rq[u], qn);
    ksum[u] = fmaf(lam, rk[u], kn);
  }
  float ss2 = ksum[0] * ksum[0] + ksum[1] * ksum[1] + ksum[2] * ksum[2] +
              ksum[3] * ksum[3];
  ss2 += __shfl_xor(ss2, 1); ss2 += __shfl_xor(ss2, 2);
  ss2 += __shfl_xor(ss2, 4); ss2 += __shfl_xor(ss2, 8);
  float inv = 1.f / fmaxf(sqrtf(ss2), 1e-12f);

  size_t ob = ((size_t)((b * 16 + h) * 4096 + t)) * 64 + j4;
  ushort4 oq, ok, ov;
  oq.x = f2bf(qtv[0]); oq.y = f2bf(qtv[1]); oq.z = f2bf(qtv[2]); oq.w = f2bf(qtv[3]);
  ok.x = f2bf(ksum[0] * inv); ok.y = f2bf(ksum[1] * inv);
  ok.z = f2bf(ksum[2] * inv); ok.w = f2bf(ksum[3] * inv);
  ov.x = f2bf(vv[0]); ov.y = f2bf(vv[1]); ov.z = f2bf(vv[2]); ov.w = f2bf(vv[3]);
  *(ushort4*)(qt + ob) = oq;
  *(ushort4*)(kt + ob) = ok;
  *(ushort4*)(vc + ob) = ov;
}

// ------------------------------------------- WY chunked gated delta scan
// 1 block (4 waves) per (b,h); 256 chunks of CW=16 steps. S in registers.
__global__ __launch_bounds__(256, 1) void scan_wy_kernel(
    const unsigned short* __restrict__ qt, const unsigned short* __restrict__ kt,
    const unsigned short* __restrict__ vc, const float* __restrict__ al,
    const float* __restrict__ be, float* __restrict__ attn) {
  __shared__ alignas(16) unsigned short Sb[64][72];     // state bf16
  __shared__ alignas(16) unsigned short Kc[2][16][72];  // K row-major [t][j]
  __shared__ alignas(16) unsigned short Qc[2][16][72];
  __shared__ alignas(16) unsigned short Vc[2][16][72];
  __shared__ alignas(16) unsigned short Kt[2][64][40];  // K^T [j][t], t>=16 zero
  __shared__ alignas(16) unsigned short Ut[64][40];     // U^T [i][t]
  __shared__ alignas(16) unsigned short Udt[64][40];    // (gpow*U)^T [i][t]
  __shared__ float KK[16][17];
  __shared__ float KQ[16][17];
  __shared__ alignas(16) float Af[16][20];
  __shared__ alignas(16) unsigned short Mb[16][72];     // cols 16..31 zero
  __shared__ float SWk[64][17];
  __shared__ float SWq[64][17];
  __shared__ alignas(16) float C0[64][20];
  __shared__ float ga[2][16], gbx[2][16];
  __shared__ alignas(16) float gb_s[16], bg_s[16], ginv_s[16], gamt_s[16],
      gpow_s[16];

  int bh = blockIdx.x;
  int b = bh >> 4, h = bh & 15;
  int tid = threadIdx.x;
  int w = tid >> 6, l = tid & 63;

  const unsigned short* kb = kt + (size_t)bh * S_ * 64;
  const unsigned short* qb = qt + (size_t)bh * S_ * 64;
  const unsigned short* vb = vc + (size_t)bh * S_ * 64;
  const float* ap = al + (size_t)bh * S_;
  const float* bp = be + (size_t)bh * S_;
  float* ob = attn + (size_t)(b * S_) * 1024 + h * 64;

  // ---- zero-init (once): state + every pad an MFMA operand can touch ----
  for (int i = tid; i < 64 * 72; i += 256) ((unsigned short*)Sb)[i] = 0;
  for (int i = tid; i < 2 * 64 * 40; i += 256) ((unsigned short*)Kt)[i] = 0;
  for (int i = tid; i < 64 * 40; i += 256) {
    ((unsigned short*)Ut)[i] = 0;
    ((unsigned short*)Udt)[i] = 0;
  }
  for (int i = tid; i < 16 * 72; i += 256) ((unsigned short*)Mb)[i] = 0;

  // S state in registers: wave w owns rows [16w,16w+16); lane holds
  // Sreg[jt][r] = S[16w + (l>>4)*4 + r][jt*16 + (l&15)]  (MFMA C/D layout)
  f32x4 Sreg[4] = {};

  // ---- prefetch chunk 0 ----
  int srow = tid >> 4, sc4 = (tid & 15) * 4;
  ushort4 pk = *(const ushort4*)(kb + (size_t)srow * 64 + sc4);
  ushort4 pq = *(const ushort4*)(qb + (size_t)srow * 64 + sc4);
  ushort4 pv = *(const ushort4*)(vb + (size_t)srow * 64 + sc4);
  float pg = 0.f;
  if (tid < 16) pg = ap[tid];
  else if (tid < 32) pg = bp[tid - 16];

  __syncthreads();  // init done

  for (int cch = 0; cch < NCH; ++cch) {
    int p = cch & 1;
    int tg0 = cch * CW;
    // ---- staging: regs -> LDS buf p (row-major + K transpose) ----
    *(ushort4*)&Kc[p][srow][sc4] = pk;
    *(ushort4*)&Qc[p][srow][sc4] = pq;
    *(ushort4*)&Vc[p][srow][sc4] = pv;
    Kt[p][sc4 + 0][srow] = pk.x;
    Kt[p][sc4 + 1][srow] = pk.y;
    Kt[p][sc4 + 2][srow] = pk.z;
    Kt[p][sc4 + 3][srow] = pk.w;
    if (tid < 16) ga[p][tid] = pg;
    else if (tid < 32) gbx[p][tid - 16] = pg;
    // prefetch next chunk
    if (cch + 1 < NCH) {
      size_t cb = (size_t)(tg0 + CW) * 64;
      pk = *(const ushort4*)(kb + cb + (size_t)srow * 64 + sc4);
      pq = *(const ushort4*)(qb + cb + (size_t)srow * 64 + sc4);
      pv = *(const ushort4*)(vb + cb + (size_t)srow * 64 + sc4);
      if (tid < 16) pg = ap[tg0 + CW + tid];
      else if (tid < 32) pg = bp[tg0 + CW + tid - 16];
    }
    __syncthreads();  // B2: chunk data + prev-chunk Sb ready

    if (w == 0) {
      // gates via DPP prefix-sum over the 16-lane row
      float av = ga[p][l & 15];
      float bt = gbx[p][l & 15];
      float la = __log2f(av);
      float pre = la;
      pre = dppadd0<0x111>(pre);  // row_shr:1
      pre = dppadd0<0x112>(pre);  // row_shr:2
      pre = dppadd0<0x114>(pre);  // row_shr:4
      pre = dppadd0<0x118>(pre);  // row_shr:8
      float tot =
          __int_as_float(__builtin_amdgcn_readlane(__float_as_int(pre), 15));
      if (l < 16) {
        float lgv = pre;
        gb_s[l] = bt;
        bg_s[l] = bt * exp2f(lgv - la);
        ginv_s[l] = exp2f(-lgv);
        gamt_s[l] = exp2f(lgv);
        gpow_s[l] = exp2f(tot - lgv);
      }
    } else if (w == 1) {
      // KK[t][s] = k_t.k_s ; KQ[t][s] = q_t.k_s
      f32x4 aK = {0.f, 0.f, 0.f, 0.f}, aQ = {0.f, 0.f, 0.f, 0.f};
#pragma unroll
      for (int kk = 0; kk < 2; kk++) {
        int ko = kk * 32 + (l >> 4) * 8;
        short8 kf = *(const short8*)&Kc[p][l & 15][ko];
        short8 qf = *(const short8*)&Qc[p][l & 15][ko];
        aK = __builtin_amdgcn_mfma_f32_16x16x32_bf16(kf, kf, aK, 0, 0, 0);
        aQ = __builtin_amdgcn_mfma_f32_16x16x32_bf16(qf, kf, aQ, 0, 0, 0);
      }
#pragma unroll
      for (int r = 0; r < 4; r++) {
        int t = (l >> 4) * 4 + r;
        KK[t][l & 15] = aK[r];
        KQ[t][l & 15] = aQ[r];
      }
    } else {
      // SWk / SWq: [64_i x 16_t] = Sb @ (Kc|Qc)^T
      const unsigned short* Bsrc = (w == 2) ? &Kc[p][0][0] : &Qc[p][0][0];
      short8 bf0, bf1;
      {
        int ko0 = (l >> 4) * 8, ko1 = 32 + (l >> 4) * 8;
        bf0 = *(const short8*)(Bsrc + (size_t)(l & 15) * 72 + ko0);
        bf1 = *(const short8*)(Bsrc + (size_t)(l & 15) * 72 + ko1);
      }
#pragma unroll
      for (int tile = 0; tile < 4; tile++) {
        f32x4 acc = {0.f, 0.f, 0.f, 0.f};
        short8 s0 = *(const short8*)&Sb[tile * 16 + (l & 15)][(l >> 4) * 8];
        short8 s1 = *(const short8*)&Sb[tile * 16 + (l & 15)][32 + (l >> 4) * 8];
        acc = __builtin_amdgcn_mfma_f32_16x16x32_bf16(s0, bf0, acc, 0, 0, 0);
        acc = __builtin_amdgcn_mfma_f32_16x16x32_bf16(s1, bf1, acc, 0, 0, 0);
#pragma unroll
        for (int r = 0; r < 4; r++) {
          int i = tile * 16 + (l >> 4) * 4 + r;
          if (w == 2) SWk[i][l & 15] = acc[r];
          else SWq[i][l & 15] = acc[r];
        }
      }
    }
    __syncthreads();  // B3

    // ---- build A, M(bf16), C0 ----
    {
      int t = tid >> 4, s = tid & 15;
      float kkv = KK[t][s], kqv = KQ[t][s];
      Af[t][s] = (s < t) ? bg_s[t] * ginv_s[s] * kkv : 0.f;
      float mv = (s <= t) ? gamt_s[t] * ginv_s[s] * kqv : 0.f;
      Mb[t][s] = f2bf(mv);
      int i = tid & 63, tq = tid >> 6;
#pragma unroll
      for (int j = 0; j < 4; j++) {
        int tt = tq * 4 + j;
        C0[i][tt] = gb_s[tt] * bf2f(Vc[p][tt][i]) - bg_s[tt] * SWk[i][tt];
      }
    }
    __syncthreads();  // B4

    // ---- forward substitution (wave 0, lane = i); reg-resident rhs ----
    if (w == 0) {
      float c0r[16], gp[16];
      *(f32x4*)&c0r[0] = *(const f32x4*)&C0[l][0];
      *(f32x4*)&c0r[4] = *(const f32x4*)&C0[l][4];
      *(f32x4*)&c0r[8] = *(const f32x4*)&C0[l][8];
      *(f32x4*)&c0r[12] = *(const f32x4*)&C0[l][12];
      *(f32x4*)&gp[0] = *(const f32x4*)&gpow_s[0];
      *(f32x4*)&gp[4] = *(const f32x4*)&gpow_s[4];
      *(f32x4*)&gp[8] = *(const f32x4*)&gpow_s[8];
      *(f32x4*)&gp[12] = *(const f32x4*)&gpow_s[12];
      float u[16];
#pragma unroll
      for (int t = 0; t < 16; t++) {
        f32x4 a0 = *(const f32x4*)&Af[t][0];
        f32x4 a1 = *(const f32x4*)&Af[t][4];
        f32x4 a2 = *(const f32x4*)&Af[t][8];
        f32x4 a3 = *(const f32x4*)&Af[t][12];
        float x = c0r[t];
#pragma unroll
        for (int s = 0; s < 16; s++) {
          if (s >= t) break;
          float av = (s < 4) ? a0[s] : (s < 8) ? a1[s - 4]
                      : (s < 12) ? a2[s - 8] : a3[s - 12];
          x = fmaf(-av, u[s], x);
        }
        u[t] = x;
      }
      short8 w0, w1, d0, d1;
#pragma unroll
      for (int j = 0; j < 8; j++) {
        w0[j] = (short)f2bf(u[j]);
        w1[j] = (short)f2bf(u[8 + j]);
        d0[j] = (short)f2bf(u[j] * gp[j]);
        d1[j] = (short)f2bf(u[8 + j] * gp[8 + j]);
      }
      *(short8*)&Ut[l][0] = w0;
      *(short8*)&Ut[l][8] = w1;
      *(short8*)&Udt[l][0] = d0;
      *(short8*)&Udt[l][8] = d1;
    }
    __syncthreads();  // B5

    // ---- O = U M^T + diag(gamt) SWq  (wave w -> i-tile w) ----
    {
      f32x4 acc = {0.f, 0.f, 0.f, 0.f};
      short8 mf = *(const short8*)&Mb[l & 15][(l >> 4) * 8];
      short8 uf = *(const short8*)&Ut[w * 16 + (l & 15)][(l >> 4) * 8];
      acc = __builtin_amdgcn_mfma_f32_16x16x32_bf16(mf, uf, acc, 0, 0, 0);
      int icol = w * 16 + (l & 15);
#pragma unroll
      for (int r = 0; r < 4; r++) {
        int t = (l >> 4) * 4 + r;
        float o = acc[r] + gamt_s[t] * SWq[icol][t];
        ob[(size_t)(tg0 + t) * 1024 + icol] = o;
      }
    }
    // ---- S <- gE*S + Ud^T K  (registers; wave w owns rows 16w..16w+15) ----
    {
      float gE = gamt_s[15];
      short8 uaf = *(const short8*)&Udt[16 * w + (l & 15)][(l >> 4) * 8];
#pragma unroll
      for (int jt = 0; jt < 4; jt++) {
        short8 kbf = *(const short8*)&Kt[p][jt * 16 + (l & 15)][(l >> 4) * 8];
        f32x4 ci;
#pragma unroll
        for (int r = 0; r < 4; r++) ci[r] = gE * Sreg[jt][r];
        ci = __builtin_amdgcn_mfma_f32_16x16x32_bf16(uaf, kbf, ci, 0, 0, 0);
        Sreg[jt] = ci;
#pragma unroll
        for (int r = 0; r < 4; r++)
          Sb[16 * w + (l >> 4) * 4 + r][jt * 16 + (l & 15)] = f2bf(ci[r]);
      }
    }
  }
}

// ------------------------------------------------ output rmsnorm -> bf16 rows
__global__ __launch_bounds__(256) void rmsnorm_out_kernel(
    const float* __restrict__ attn, const float* __restrict__ onw,
    unsigned short* __restrict__ normed) {
  int m = blockIdx.x, tid = threadIdx.x;
  const float* row = attn + (size_t)m * 1024;
  float xv[4];
  *(float4*)xv = *(const float4*)(row + tid * 4);
  float ss = xv[0] * xv[0] + xv[1] * xv[1] + xv[2] * xv[2] + xv[3] * xv[3];
#pragma unroll
  for (int o = 1; o < 64; o <<= 1) ss += __shfl_xor(ss, o);
  __shared__ float wss[4];
  if ((tid & 63) == 0) wss[tid >> 6] = ss;
  __syncthreads();
  float tot = wss[0] + wss[1] + wss[2] + wss[3];
  float sc = rsqrtf(tot * (1.f / 1024.f) + 1e-6f);
  float wv[4];
  *(float4*)wv = *(const float4*)(onw + tid * 4);
  ushort4 o4;
  o4.x = f2bf(xv[0] * sc * wv[0]);
  o4.y = f2bf(xv[1] * sc * wv[1]);
  o4.z = f2bf(xv[2] * sc * wv[2]);
  o4.w = f2bf(xv[3] * sc * wv[3]);
  *(ushort4*)(normed + (size_t)m * 1024 + tid * 4) = o4;
}

// ---------------------------------------------------------------------------
extern "C" void kernel_launch(void* const* d_in, const int* in_sizes, int n_in,
                              void* d_out, int out_size, void* d_ws,
                              size_t ws_size, hipStream_t stream) {
  const float* x = (const float*)d_in[0];
  const float* Wq = (const float*)d_in[1];
  const float* Wk = (const float*)d_in[2];
  const float* Wv = (const float*)d_in[3];
  const float* Wo = (const float*)d_in[4];
  const float* conv_q = (const float*)d_in[5];
  const float* conv_k = (const float*)d_in[6];
  const float* conv_v = (const float*)d_in[7];
  const float* Wf = (const float*)d_in[8];
  const float* bfv = (const float*)d_in[9];
  const float* Wl = (const float*)d_in[10];
  const float* blv = (const float*)d_in[11];
  const float* gs = (const float*)d_in[14];
  const float* qn_w = (const float*)d_in[15];
  const float* kn_w = (const float*)d_in[16];
  const float* on_w = (const float*)d_in[17];

  char* ws = (char*)d_ws;
  size_t used = 0;
  auto alloc = [&](size_t bytes) -> void* {
    void* p = (void*)(ws + used);
    used += (bytes + 255) & ~(size_t)255;
    return p;
  };
  unsigned short* xb = (unsigned short*)alloc((size_t)M_ * D_ * 2);
  unsigned short* wqkv_t = (unsigned short*)alloc((size_t)3072 * 1024 * 2);
  unsigned short* wr_t = (unsigned short*)alloc((size_t)1536 * 1024 * 2);
  unsigned short* wo_t = (unsigned short*)alloc((size_t)1024 * 1024 * 2);
  unsigned short* wfl = (unsigned short*)alloc((size_t)32 * 1024 * 2);
  unsigned short* xqkv = (unsigned short*)alloc((size_t)M_ * 3072 * 2);
  unsigned short* rqk = (unsigned short*)alloc((size_t)M_ * 1536 * 2);
  unsigned short* qt = (unsigned short*)alloc((size_t)M_ * 1024 * 2);
  unsigned short* kt = (unsigned short*)alloc((size_t)M_ * 1024 * 2);
  unsigned short* vc = (unsigned short*)alloc((size_t)M_ * 1024 * 2);
  float* alpha = (float*)alloc((size_t)B_ * H_ * S_ * 4);
  float* beta = (float*)alloc((size_t)B_ * H_ * S_ * 4);
  float* attn = (float*)xqkv;    // alias (xqkv dead after prep)
  unsigned short* normed = rqk;  // alias (rqk dead after prep)

  if (used > ws_size) return;

  cast_bf16_kernel<<<2048, 256, 0, stream>>>(x, xb, M_ * D_ / 4);

  dim3 tb(32, 8);
  transpose_w_kernel<<<dim3(32, 32), tb, 0, stream>>>(Wq, wqkv_t, 1024, 1024);
  transpose_w_kernel<<<dim3(32, 32), tb, 0, stream>>>(
      Wk, wqkv_t + (size_t)1024 * 1024, 1024, 1024);
  transpose_w_kernel<<<dim3(32, 32), tb, 0, stream>>>(
      Wv, wqkv_t + (size_t)2048 * 1024, 1024, 1024);
  transpose_w_kernel<<<dim3(24, 32), tb, 0, stream>>>(
      (const float*)d_in[12], wr_t, 1024, 768);
  transpose_w_kernel<<<dim3(24, 32), tb, 0, stream>>>(
      (const float*)d_in[13], wr_t + (size_t)768 * 1024, 1024, 768);
  transpose_w_kernel<<<dim3(32, 32), tb, 0, stream>>>(Wo, wo_t, 1024, 1024);
  pack_wfl_kernel<<<128, 256, 0, stream>>>(Wf, Wl, wfl);

  gemm_bt_kernel<true><<<64 * 24, 256, 0, stream>>>(xb, wqkv_t, xqkv, M_, 3072, 1024);
  gemm_bt_kernel<true><<<64 * 12, 256, 0, stream>>>(xb, wr_t, rqk, M_, 1536, 1024);

  fl_gemm_kernel<<<64, 256, 0, stream>>>(xb, wfl, bfv, blv, alpha, beta);

  prep_kernel<<<M_, 256, 0, stream>>>(xqkv, rqk, conv_q, conv_k, conv_v, gs,
                                      qn_w, kn_w, qt, kt, vc);

  scan_wy_kernel<<<B_ * H_, 256, 0, stream>>>(qt, kt, vc, alpha, beta, attn);

  rmsnorm_out_kernel<<<M_, 256, 0, stream>>>(attn, on_w, normed);

  gemm_bt_kernel<false><<<64 * 8, 256, 0, stream>>>(normed, wo_t, (float*)d_out,
                                                    M_, 1024, 1024);
}

// Round 11
// 667.570 us; speedup vs baseline: 1.5953x; 1.4070x over previous
//
#include <hip/hip_runtime.h>

// ---------------------------------------------------------------------------
// GDN attention block, MI355X (gfx950).
//   scan: WY/chunked gated delta rule, CW=16, row-split:
//     wy_pre (8192 tiles, parallel): A f32 / M bf16 / gate vecs per chunk.
//     scan_wy (128 blocks = 32 bh x 4 rowgroups of 16 i-rows): per chunk
//       SWk/SWq MFMA, 16-lane triangular solve, O MFMA, S-update MFMA
//       (S in regs). 3 barriers/chunk.
// Rest of pipeline unchanged (bf16 MFMA GEMMs, fused prep, rmsnorm, Wo).
// ---------------------------------------------------------------------------

typedef __attribute__((ext_vector_type(8))) short short8;
typedef __attribute__((ext_vector_type(4))) float f32x4;

#define B_ 2
#define S_ 4096
#define D_ 1024
#define H_ 16
#define R_ 48
#define M_ 8192  // B*S
#define CW 16
#define NCH (S_ / CW)

__device__ __forceinline__ unsigned short f2bf(float f) {
  unsigned u = __float_as_uint(f);
  u += 0x7FFFu + ((u >> 16) & 1u);
  return (unsigned short)(u >> 16);
}
__device__ __forceinline__ float bf2f(unsigned short u) {
  return __uint_as_float(((unsigned)u) << 16);
}

#define GLDS16(g, l) __builtin_amdgcn_global_load_lds(                        \
    (const __attribute__((address_space(1))) unsigned int*)(g),              \
    (__attribute__((address_space(3))) unsigned int*)(l), 16, 0, 0)

// --------------------------------------------------------------- cast x->bf16
__global__ __launch_bounds__(256) void cast_bf16_kernel(
    const float* __restrict__ in, unsigned short* __restrict__ out, int n4) {
  int i = blockIdx.x * 256 + threadIdx.x;
  for (; i < n4; i += gridDim.x * 256) {
    float4 v = ((const float4*)in)[i];
    ushort4 o;
    o.x = f2bf(v.x); o.y = f2bf(v.y); o.z = f2bf(v.z); o.w = f2bf(v.w);
    ((ushort4*)out)[i] = o;
  }
}

// ------------------------------------------------- W[K][N] -> Wt[N][K] (bf16)
__global__ void transpose_w_kernel(const float* __restrict__ W,
                                   unsigned short* __restrict__ Wt,
                                   int Kd, int N) {
  __shared__ float tile[32][33];
  int n0 = blockIdx.x * 32, k0 = blockIdx.y * 32;
  int tx = threadIdx.x, ty = threadIdx.y;  // 32 x 8
#pragma unroll
  for (int i = 0; i < 32; i += 8)
    tile[ty + i][tx] = W[(size_t)(k0 + ty + i) * N + n0 + tx];
  __syncthreads();
#pragma unroll
  for (int i = 0; i < 32; i += 8)
    Wt[(size_t)(n0 + ty + i) * Kd + k0 + tx] = f2bf(tile[tx][ty + i]);
}

// -------------------------------------- pack [Wf|Wl] -> wfl[32][1024] bf16
__global__ __launch_bounds__(256) void pack_wfl_kernel(
    const float* __restrict__ Wf, const float* __restrict__ Wl,
    unsigned short* __restrict__ wfl) {
  int o = blockIdx.x * 256 + threadIdx.x;  // 32768 total
  int j = o >> 10, k = o & 1023;
  float v = (j < 16) ? Wf[k * 16 + j] : Wl[k * 16 + (j - 16)];
  wfl[o] = f2bf(v);
}

// ------------------------------------------------------------- bf16 MFMA GEMM
template <bool BF16OUT>
__global__ __launch_bounds__(256) void gemm_bt_kernel(
    const unsigned short* __restrict__ A, const unsigned short* __restrict__ Bt,
    void* __restrict__ Cv, int M, int N, int Kd) {
  __shared__ alignas(16) unsigned short lds[2 * 128 * 64];  // 32 KiB
  unsigned short* ldsA = lds;
  unsigned short* ldsB = lds + 128 * 64;
  int tid = threadIdx.x;
  int wave = tid >> 6, lane = tid & 63;
  int nBlocks = N >> 7;
  int bm = blockIdx.x / nBlocks, bn = blockIdx.x % nBlocks;
  int m0 = bm << 7, n0 = bn << 7;
  int wm = (wave >> 1) << 6, wn = (wave & 1) << 6;

  f32x4 acc[4][4] = {};

  int rowInChunk = lane >> 3;
  int kOff = (lane & 7) * 8;

  const unsigned short* Abase = A + (size_t)m0 * Kd;
  const unsigned short* Bbase = Bt + (size_t)n0 * Kd;

  for (int k0 = 0; k0 < Kd; k0 += 64) {
    __syncthreads();
#pragma unroll
    for (int r = 0; r < 4; r++) {
      int c = wave * 4 + r;
      int row = c * 8 + rowInChunk;
      GLDS16(Abase + (size_t)row * Kd + k0 + kOff, ldsA + c * 512);
    }
#pragma unroll
    for (int r = 0; r < 4; r++) {
      int c = wave * 4 + r;
      int row = c * 8 + rowInChunk;
      GLDS16(Bbase + (size_t)row * Kd + k0 + kOff, ldsB + c * 512);
    }
    asm volatile("s_waitcnt vmcnt(0)" ::: "memory");
    __syncthreads();
#pragma unroll
    for (int kk = 0; kk < 2; kk++) {
      short8 af[4], bfr[4];
      int kb = kk * 32 + (lane >> 4) * 8;
#pragma unroll
      for (int i = 0; i < 4; i++) {
        int ar = wm + i * 16 + (lane & 15);
        af[i] = *(const short8*)(ldsA + ar * 64 + kb);
        int br = wn + i * 16 + (lane & 15);
        bfr[i] = *(const short8*)(ldsB + br * 64 + kb);
      }
#pragma unroll
      for (int i = 0; i < 4; i++)
#pragma unroll
        for (int j = 0; j < 4; j++)
          acc[i][j] = __builtin_amdgcn_mfma_f32_16x16x32_bf16(
              af[i], bfr[j], acc[i][j], 0, 0, 0);
    }
  }
  int cr = (lane >> 4) * 4;
  int cc = lane & 15;
#pragma unroll
  for (int i = 0; i < 4; i++)
#pragma unroll
    for (int j = 0; j < 4; j++)
#pragma unroll
      for (int rg = 0; rg < 4; rg++) {
        int row = m0 + wm + i * 16 + cr + rg;
        int col = n0 + wn + j * 16 + cc;
        if (BF16OUT)
          ((unsigned short*)Cv)[(size_t)row * N + col] = f2bf(acc[i][j][rg]);
        else
          ((float*)Cv)[(size_t)row * N + col] = acc[i][j][rg];
      }
}

// ---------------------------- alpha/beta via MFMA: [8192x1024]@[32x1024]^T
__global__ __launch_bounds__(256) void fl_gemm_kernel(
    const unsigned short* __restrict__ xb, const unsigned short* __restrict__ wfl,
    const float* __restrict__ bfv, const float* __restrict__ blv,
    float* __restrict__ alpha, float* __restrict__ beta) {
  __shared__ alignas(16) unsigned short ldsA[128 * 64];
  __shared__ alignas(16) unsigned short ldsB[32 * 64];
  int tid = threadIdx.x, wave = tid >> 6, lane = tid & 63;
  int m0 = blockIdx.x << 7;
  f32x4 acc[2][2] = {};
  int rowInChunk = lane >> 3, kOff = (lane & 7) * 8;
  const unsigned short* Abase = xb + (size_t)m0 * 1024;

  for (int k0 = 0; k0 < 1024; k0 += 64) {
    __syncthreads();
#pragma unroll
    for (int r = 0; r < 4; r++) {
      int ch = wave * 4 + r;
      int row = ch * 8 + rowInChunk;
      GLDS16(Abase + (size_t)row * 1024 + k0 + kOff, ldsA + ch * 512);
    }
    {
      int row = wave * 8 + rowInChunk;
      GLDS16(wfl + (size_t)row * 1024 + k0 + kOff, ldsB + wave * 512);
    }
    asm volatile("s_waitcnt vmcnt(0)" ::: "memory");
    __syncthreads();
#pragma unroll
    for (int kk = 0; kk < 2; kk++) {
      int kb2 = kk * 32 + (lane >> 4) * 8;
      short8 af[2], bfr[2];
#pragma unroll
      for (int i = 0; i < 2; i++)
        af[i] = *(const short8*)(ldsA + (wave * 32 + i * 16 + (lane & 15)) * 64 + kb2);
#pragma unroll
      for (int j = 0; j < 2; j++)
        bfr[j] = *(const short8*)(ldsB + (j * 16 + (lane & 15)) * 64 + kb2);
#pragma unroll
      for (int i = 0; i < 2; i++)
#pragma unroll
        for (int j = 0; j < 2; j++)
          acc[i][j] = __builtin_amdgcn_mfma_f32_16x16x32_bf16(
              af[i], bfr[j], acc[i][j], 0, 0, 0);
    }
  }
  int cr = (lane >> 4) * 4, cc = lane & 15;
#pragma unroll
  for (int i = 0; i < 2; i++)
#pragma unroll
    for (int j = 0; j < 2; j++)
#pragma unroll
      for (int rg = 0; rg < 4; rg++) {
        int row = m0 + wave * 32 + i * 16 + cr + rg;
        int col = j * 16 + cc;
        float z = acc[i][j][rg] + ((col < 16) ? bfv[col] : blv[col - 16]);
        float s = 1.f / (1.f + __expf(-z));
        int bb = row >> 12, tt = row & 4095, hh = col & 15;
        float* dst = (col < 16) ? alpha : beta;
        dst[((size_t)(bb * 16 + hh)) * 4096 + tt] = s;
      }
}

// ------------------------ conv + rmsnorm + low-rank mix + k-tilde normalize
__global__ __launch_bounds__(256) void prep_kernel(
    const unsigned short* __restrict__ xqkv, const unsigned short* __restrict__ rqk,
    const float* __restrict__ cq, const float* __restrict__ ck,
    const float* __restrict__ cv, const float* __restrict__ gs,
    const float* __restrict__ qnw, const float* __restrict__ knw,
    unsigned short* __restrict__ qt, unsigned short* __restrict__ kt,
    unsigned short* __restrict__ vc) {
  int m = blockIdx.x;
  int b = m >> 12, t = m & 4095;
  int tid = threadIdx.x;
  int c4 = tid << 2;
  int h = c4 >> 6;
  int j4 = c4 & 63;

  float wq[4][4], wk[4][4], wv[4][4];
#pragma unroll
  for (int u = 0; u < 4; u++) {
    *(float4*)wq[u] = *(const float4*)(cq + (c4 + u) * 4);
    *(float4*)wk[u] = *(const float4*)(ck + (c4 + u) * 4);
    *(float4*)wv[u] = *(const float4*)(cv + (c4 + u) * 4);
  }
  float qv[4] = {0, 0, 0, 0}, kv[4] = {0, 0, 0, 0}, vv[4] = {0, 0, 0, 0};
#pragma unroll
  for (int j = 0; j < 4; j++) {
    int tt = t + j - 3;
    if (tt < 0) continue;
    const unsigned short* xr = xqkv + ((size_t)((b << 12) + tt)) * 3072;
    ushort4 uq = *(const ushort4*)(xr + c4);
    ushort4 uk = *(const ushort4*)(xr + 1024 + c4);
    ushort4 uv = *(const ushort4*)(xr + 2048 + c4);
    float xq[4] = {bf2f(uq.x), bf2f(uq.y), bf2f(uq.z), bf2f(uq.w)};
    float xk[4] = {bf2f(uk.x), bf2f(uk.y), bf2f(uk.z), bf2f(uk.w)};
    float xv[4] = {bf2f(uv.x), bf2f(uv.y), bf2f(uv.z), bf2f(uv.w)};
#pragma unroll
    for (int u = 0; u < 4; u++) {
      qv[u] = fmaf(wq[u][j], xq[u], qv[u]);
      kv[u] = fmaf(wk[u][j], xk[u], kv[u]);
      vv[u] = fmaf(wv[u][j], xv[u], vv[u]);
    }
  }
  float ssq = qv[0] * qv[0] + qv[1] * qv[1] + qv[2] * qv[2] + qv[3] * qv[3];
  ssq += __shfl_xor(ssq, 1); ssq += __shfl_xor(ssq, 2);
  ssq += __shfl_xor(ssq, 4); ssq += __shfl_xor(ssq, 8);
  float qsc = rsqrtf(ssq * (1.f / 64.f) + 1e-6f);
  float ssk = kv[0] * kv[0] + kv[1] * kv[1] + kv[2] * kv[2] + kv[3] * kv[3];
  ssk += __shfl_xor(ssk, 1); ssk += __shfl_xor(ssk, 2);
  ssk += __shfl_xor(ssk, 4); ssk += __shfl_xor(ssk, 8);
  float ksc = rsqrtf(ssk * (1.f / 64.f) + 1e-6f);

  float lam = fabsf(gs[h]);
  float rq[4] = {0, 0, 0, 0}, rk[4] = {0, 0, 0, 0};
  if (j4 < R_) {
    const unsigned short* rr = rqk + (size_t)m * 1536;
    ushort4 uq = *(const ushort4*)(rr + h * R_ + j4);
    ushort4 uk = *(const ushort4*)(rr + 768 + h * R_ + j4);
    rq[0] = bf2f(uq.x); rq[1] = bf2f(uq.y); rq[2] = bf2f(uq.z); rq[3] = bf2f(uq.w);
    rk[0] = bf2f(uk.x); rk[1] = bf2f(uk.y); rk[2] = bf2f(uk.z); rk[3] = bf2f(uk.w);
  }
  float qtv[4], ksum[4];
#pragma unroll
  for (int u = 0; u < 4; u++) {
    float qn = qv[u] * qsc * qnw[j4 + u];
    float kn = kv[u] * ksc * knw[j4 + u];
    qtv[u] = fmaf(lam, rq[u], qn);
    ksum[u] = fmaf(lam, rk[u], kn);
  }
  float ss2 = ksum[0] * ksum[0] + ksum[1] * ksum[1] + ksum[2] * ksum[2] +
              ksum[3] * ksum[3];
  ss2 += __shfl_xor(ss2, 1); ss2 += __shfl_xor(ss2, 2);
  ss2 += __shfl_xor(ss2, 4); ss2 += __shfl_xor(ss2, 8);
  float inv = 1.f / fmaxf(sqrtf(ss2), 1e-12f);

  size_t ob = ((size_t)((b * 16 + h) * 4096 + t)) * 64 + j4;
  ushort4 oq, ok, ov;
  oq.x = f2bf(qtv[0]); oq.y = f2bf(qtv[1]); oq.z = f2bf(qtv[2]); oq.w = f2bf(qtv[3]);
  ok.x = f2bf(ksum[0] * inv); ok.y = f2bf(ksum[1] * inv);
  ok.z = f2bf(ksum[2] * inv); ok.w = f2bf(ksum[3] * inv);
  ov.x = f2bf(vv[0]); ov.y = f2bf(vv[1]); ov.z = f2bf(vv[2]); ov.w = f2bf(vv[3]);
  *(ushort4*)(qt + ob) = oq;
  *(ushort4*)(kt + ob) = ok;
  *(ushort4*)(vc + ob) = ov;
}

// ---------------------------------------- WY pre-pass: A,M,gates per chunk
// 1 wave per (bh,chunk): KK/KQ via MFMA from global; gates via shfl prefix.
__global__ __launch_bounds__(64) void wy_pre_kernel(
    const unsigned short* __restrict__ qt, const unsigned short* __restrict__ kt,
    const float* __restrict__ al, const float* __restrict__ be,
    float* __restrict__ Aw, unsigned short* __restrict__ Mw,
    float* __restrict__ Gw) {
  __shared__ float g5[5][16];  // gb,bg,gamt,gpow,ginv
  int tile = blockIdx.x;
  int bh = tile >> 8, c = tile & 255;
  int tg = c * CW;
  int l = threadIdx.x;

  const unsigned short* kb = kt + (size_t)bh * S_ * 64 + (size_t)tg * 64;
  const unsigned short* qb = qt + (size_t)bh * S_ * 64 + (size_t)tg * 64;

  // gates (lanes 0..15)
  float a_ = 1.f, bt_ = 0.f;
  if (l < 16) {
    a_ = al[(size_t)bh * S_ + tg + l];
    bt_ = be[(size_t)bh * S_ + tg + l];
  }
  float la = __log2f(a_);
  float pre = la;
  {
    float y;
    y = __shfl_up(pre, 1);  if (l >= 1) pre += y;
    y = __shfl_up(pre, 2);  if (l >= 2) pre += y;
    y = __shfl_up(pre, 4);  if (l >= 4) pre += y;
    y = __shfl_up(pre, 8);  if (l >= 8) pre += y;
  }
  float tot = __shfl(pre, 15);
  if (l < 16) {
    g5[0][l] = bt_;
    g5[1][l] = bt_ * exp2f(pre - la);
    g5[2][l] = exp2f(pre);
    g5[3][l] = exp2f(tot - pre);
    g5[4][l] = exp2f(-pre);
  }

  // KK, KQ via MFMA with direct global fragments
  short8 kf0 = *(const short8*)(kb + (size_t)(l & 15) * 64 + (l >> 4) * 8);
  short8 kf1 = *(const short8*)(kb + (size_t)(l & 15) * 64 + 32 + (l >> 4) * 8);
  short8 qf0 = *(const short8*)(qb + (size_t)(l & 15) * 64 + (l >> 4) * 8);
  short8 qf1 = *(const short8*)(qb + (size_t)(l & 15) * 64 + 32 + (l >> 4) * 8);
  f32x4 aK = {0.f, 0.f, 0.f, 0.f}, aQ = {0.f, 0.f, 0.f, 0.f};
  aK = __builtin_amdgcn_mfma_f32_16x16x32_bf16(kf0, kf0, aK, 0, 0, 0);
  aK = __builtin_amdgcn_mfma_f32_16x16x32_bf16(kf1, kf1, aK, 0, 0, 0);
  aQ = __builtin_amdgcn_mfma_f32_16x16x32_bf16(qf0, kf0, aQ, 0, 0, 0);
  aQ = __builtin_amdgcn_mfma_f32_16x16x32_bf16(qf1, kf1, aQ, 0, 0, 0);

  __syncthreads();  // g5 visible

  int s = l & 15;
  float* Ao = Aw + (size_t)tile * 256;
  unsigned short* Mo = Mw + (size_t)tile * 256;
#pragma unroll
  for (int r = 0; r < 4; r++) {
    int t = (l >> 4) * 4 + r;
    float av = (s < t) ? g5[1][t] * g5[4][s] * aK[r] : 0.f;
    float mv = (s <= t) ? g5[2][t] * g5[4][s] * aQ[r] : 0.f;
    Ao[t * 16 + s] = av;
    Mo[t * 16 + s] = f2bf(mv);
  }
  if (l < 64) Gw[(size_t)tile * 64 + l] = g5[l >> 4][l & 15];
}

// ------------------------------------------- WY main scan (row-split)
// 128 blocks: bh = blk&31, rowgroup rg = blk>>5 (i-rows rg*16..+16).
// S (16x64) in regs (wave w owns j-tile w). 3 barriers/chunk.
__global__ __launch_bounds__(256, 1) void scan_wy_kernel(
    const unsigned short* __restrict__ qt, const unsigned short* __restrict__ kt,
    const unsigned short* __restrict__ vc, const float* __restrict__ Aw,
    const unsigned short* __restrict__ Mw, const float* __restrict__ Gw,
    float* __restrict__ attn) {
  __shared__ alignas(16) unsigned short Kc[2][16][72];
  __shared__ alignas(16) unsigned short Qc[2][16][72];
  __shared__ alignas(16) unsigned short KT[2][64][40];  // [j][t], t>=16 zero
  __shared__ alignas(16) unsigned short Vc[2][16][24];  // [t][i]
  __shared__ alignas(16) float Af[2][16][20];
  __shared__ alignas(16) unsigned short Mb[2][16][40];  // cols>=16 zero
  __shared__ alignas(16) float G[2][64];  // gb|bg|gamt|gpow
  __shared__ alignas(16) float SWk[16][20];
  __shared__ alignas(16) float SWq[16][20];
  __shared__ alignas(16) unsigned short UT[16][40];   // [i][s], s>=16 zero
  __shared__ alignas(16) unsigned short Udt[16][40];  // [i][t], t>=16 zero
  __shared__ alignas(16) unsigned short Sb[16][72];   // S row-major bf16

  int blk = blockIdx.x;
  int bh = blk & 31, rg = blk >> 5;
  int b = bh >> 4, h = bh & 15;
  int tid = threadIdx.x;
  int w = tid >> 6, l = tid & 63;

  const unsigned short* kb = kt + (size_t)bh * S_ * 64;
  const unsigned short* qb = qt + (size_t)bh * S_ * 64;
  const unsigned short* vb = vc + (size_t)bh * S_ * 64 + rg * 16;
  const float* Ab = Aw + (size_t)bh * 256 * 256;
  const unsigned short* Mbg = Mw + (size_t)bh * 256 * 256;
  const float* Gb = Gw + (size_t)bh * 256 * 64;
  float* ob = attn + (size_t)(b * S_) * 1024 + h * 64 + rg * 16;

  // zero pads + Sb
  for (int i = tid; i < 2 * 64 * 40; i += 256) ((unsigned short*)KT)[i] = 0;
  for (int i = tid; i < 2 * 16 * 40; i += 256) ((unsigned short*)Mb)[i] = 0;
  for (int i = tid; i < 16 * 40; i += 256) {
    ((unsigned short*)UT)[i] = 0;
    ((unsigned short*)Udt)[i] = 0;
  }
  for (int i = tid; i < 16 * 72; i += 256) ((unsigned short*)Sb)[i] = 0;

  f32x4 Sreg = {0.f, 0.f, 0.f, 0.f};  // S[(l>>4)*4+r][16w + (l&15)]

  // prefetch chunk 0
  int trow = tid >> 4, tc4 = (tid & 15) * 4;
  ushort4 pk = *(const ushort4*)(kb + (size_t)trow * 64 + tc4);
  ushort4 pq = *(const ushort4*)(qb + (size_t)trow * 64 + tc4);
  unsigned short pv = vb[(size_t)trow * 64 + (tid & 15)];
  float pa = Ab[tid];
  unsigned short pm = Mbg[tid];
  float pg = (tid < 64) ? Gb[tid] : 0.f;

  __syncthreads();  // zero-init visible

  for (int c = 0; c < NCH; ++c) {
    int p = c & 1;
    int tg0 = c * CW;
    // ---- stage buf p ----
    *(ushort4*)&Kc[p][trow][tc4] = pk;
    *(ushort4*)&Qc[p][trow][tc4] = pq;
    KT[p][tc4 + 0][trow] = pk.x;
    KT[p][tc4 + 1][trow] = pk.y;
    KT[p][tc4 + 2][trow] = pk.z;
    KT[p][tc4 + 3][trow] = pk.w;
    Vc[p][trow][tid & 15] = pv;
    Af[p][trow][tid & 15] = pa;
    Mb[p][trow][tid & 15] = pm;
    if (tid < 64) G[p][tid] = pg;
    // ---- prefetch c+1 ----
    if (c + 1 < NCH) {
      size_t cb = (size_t)(tg0 + CW) * 64;
      pk = *(const ushort4*)(kb + cb + (size_t)trow * 64 + tc4);
      pq = *(const ushort4*)(qb + cb + (size_t)trow * 64 + tc4);
      pv = vb[cb + (size_t)trow * 64 + (tid & 15)];
      size_t t2 = (size_t)(c + 1) * 256;
      pa = Ab[t2 + tid];
      pm = Mbg[t2 + tid];
      if (tid < 64) pg = Gb[(size_t)(c + 1) * 64 + tid];
    }
    __syncthreads();  // A: staging + prev Sb visible

    // ---- phase1: SWk (w0), SWq (w1) = Sb @ {K|Q}^T ----
    if (w < 2) {
      const unsigned short* Bsrc = (w == 0) ? &Kc[p][0][0] : &Qc[p][0][0];
      short8 s0 = *(const short8*)&Sb[l & 15][(l >> 4) * 8];
      short8 s1 = *(const short8*)&Sb[l & 15][32 + (l >> 4) * 8];
      short8 b0 = *(const short8*)(Bsrc + (size_t)(l & 15) * 72 + (l >> 4) * 8);
      short8 b1 =
          *(const short8*)(Bsrc + (size_t)(l & 15) * 72 + 32 + (l >> 4) * 8);
      f32x4 acc = {0.f, 0.f, 0.f, 0.f};
      acc = __builtin_amdgcn_mfma_f32_16x16x32_bf16(s0, b0, acc, 0, 0, 0);
      acc = __builtin_amdgcn_mfma_f32_16x16x32_bf16(s1, b1, acc, 0, 0, 0);
      float* dst = (w == 0) ? &SWk[0][0] : &SWq[0][0];
#pragma unroll
      for (int r = 0; r < 4; r++)
        dst[((l >> 4) * 4 + r) * 20 + (l & 15)] = acc[r];
    }
    __syncthreads();  // B

    // ---- phase2: triangular solve (w0, lanes 0..15; lane = i-col) ----
    if (w == 0 && l < 16) {
      float swk[16];
      *(f32x4*)&swk[0] = *(const f32x4*)&SWk[l][0];
      *(f32x4*)&swk[4] = *(const f32x4*)&SWk[l][4];
      *(f32x4*)&swk[8] = *(const f32x4*)&SWk[l][8];
      *(f32x4*)&swk[12] = *(const f32x4*)&SWk[l][12];
      float c0r[16];
#pragma unroll
      for (int t = 0; t < 16; t++)
        c0r[t] = G[p][t] * bf2f(Vc[p][t][l]) - G[p][16 + t] * swk[t];
      float u[16];
#pragma unroll
      for (int t = 0; t < 16; t++) {
        float x = c0r[t];
#pragma unroll
        for (int s = 0; s < t; s++) x = fmaf(-Af[p][t][s], u[s], x);
        u[t] = x;
      }
      short8 o0, o1, d0, d1;
#pragma unroll
      for (int j = 0; j < 8; j++) {
        o0[j] = (short)f2bf(u[j]);
        o1[j] = (short)f2bf(u[8 + j]);
        d0[j] = (short)f2bf(u[j] * G[p][48 + j]);
        d1[j] = (short)f2bf(u[8 + j] * G[p][48 + 8 + j]);
      }
      *(short8*)&UT[l][0] = o0;
      *(short8*)&UT[l][8] = o1;
      *(short8*)&Udt[l][0] = d0;
      *(short8*)&Udt[l][8] = d1;
    }
    __syncthreads();  // C

    // ---- phase3: O (w0) + S update (all waves) ----
    if (w == 0) {
      short8 mfr = *(const short8*)&Mb[p][l & 15][(l >> 4) * 8];
      short8 ufr = *(const short8*)&UT[l & 15][(l >> 4) * 8];
      f32x4 acc = {0.f, 0.f, 0.f, 0.f};
      acc = __builtin_amdgcn_mfma_f32_16x16x32_bf16(mfr, ufr, acc, 0, 0, 0);
#pragma unroll
      for (int r = 0; r < 4; r++) {
        int t = (l >> 4) * 4 + r;
        float o = acc[r] + G[p][32 + t] * SWq[l & 15][t];
        ob[(size_t)(tg0 + t) * 1024 + (l & 15)] = o;
      }
    }
    {
      float gE = G[p][32 + 15];
      short8 ud = *(const short8*)&Udt[l & 15][(l >> 4) * 8];
      short8 ktf = *(const short8*)&KT[p][16 * w + (l & 15)][(l >> 4) * 8];
      f32x4 ci;
#pragma unroll
      for (int r = 0; r < 4; r++) ci[r] = gE * Sreg[r];
      ci = __builtin_amdgcn_mfma_f32_16x16x32_bf16(ud, ktf, ci, 0, 0, 0);
      Sreg = ci;
#pragma unroll
      for (int r = 0; r < 4; r++)
        Sb[(l >> 4) * 4 + r][16 * w + (l & 15)] = f2bf(ci[r]);
    }
  }
}

// ------------------------------------------------ output rmsnorm -> bf16 rows
__global__ __launch_bounds__(256) void rmsnorm_out_kernel(
    const float* __restrict__ attn, const float* __restrict__ onw,
    unsigned short* __restrict__ normed) {
  int m = blockIdx.x, tid = threadIdx.x;
  const float* row = attn + (size_t)m * 1024;
  float xv[4];
  *(float4*)xv = *(const float4*)(row + tid * 4);
  float ss = xv[0] * xv[0] + xv[1] * xv[1] + xv[2] * xv[2] + xv[3] * xv[3];
#pragma unroll
  for (int o = 1; o < 64; o <<= 1) ss += __shfl_xor(ss, o);
  __shared__ float wss[4];
  if ((tid & 63) == 0) wss[tid >> 6] = ss;
  __syncthreads();
  float tot = wss[0] + wss[1] + wss[2] + wss[3];
  float sc = rsqrtf(tot * (1.f / 1024.f) + 1e-6f);
  float wv[4];
  *(float4*)wv = *(const float4*)(onw + tid * 4);
  ushort4 o4;
  o4.x = f2bf(xv[0] * sc * wv[0]);
  o4.y = f2bf(xv[1] * sc * wv[1]);
  o4.z = f2bf(xv[2] * sc * wv[2]);
  o4.w = f2bf(xv[3] * sc * wv[3]);
  *(ushort4*)(normed + (size_t)m * 1024 + tid * 4) = o4;
}

// ---------------------------------------------------------------------------
extern "C" void kernel_launch(void* const* d_in, const int* in_sizes, int n_in,
                              void* d_out, int out_size, void* d_ws,
                              size_t ws_size, hipStream_t stream) {
  const float* x = (const float*)d_in[0];
  const float* Wq = (const float*)d_in[1];
  const float* Wk = (const float*)d_in[2];
  const float* Wv = (const float*)d_in[3];
  const float* Wo = (const float*)d_in[4];
  const float* conv_q = (const float*)d_in[5];
  const float* conv_k = (const float*)d_in[6];
  const float* conv_v = (const float*)d_in[7];
  const float* Wf = (const float*)d_in[8];
  const float* bfv = (const float*)d_in[9];
  const float* Wl = (const float*)d_in[10];
  const float* blv = (const float*)d_in[11];
  const float* gs = (const float*)d_in[14];
  const float* qn_w = (const float*)d_in[15];
  const float* kn_w = (const float*)d_in[16];
  const float* on_w = (const float*)d_in[17];

  char* ws = (char*)d_ws;
  size_t used = 0;
  auto alloc = [&](size_t bytes) -> void* {
    void* p = (void*)(ws + used);
    used += (bytes + 255) & ~(size_t)255;
    return p;
  };
  unsigned short* xb = (unsigned short*)alloc((size_t)M_ * D_ * 2);  // 16MB
  unsigned short* wqkv_t = (unsigned short*)alloc((size_t)3072 * 1024 * 2);
  unsigned short* wr_t = (unsigned short*)alloc((size_t)1536 * 1024 * 2);
  unsigned short* wo_t = (unsigned short*)alloc((size_t)1024 * 1024 * 2);
  unsigned short* wfl = (unsigned short*)alloc((size_t)32 * 1024 * 2);
  unsigned short* xqkv = (unsigned short*)alloc((size_t)M_ * 3072 * 2);
  unsigned short* rqk = (unsigned short*)alloc((size_t)M_ * 1536 * 2);
  unsigned short* qt = (unsigned short*)alloc((size_t)M_ * 1024 * 2);
  unsigned short* kt = (unsigned short*)alloc((size_t)M_ * 1024 * 2);
  unsigned short* vc = (unsigned short*)alloc((size_t)M_ * 1024 * 2);
  float* alpha = (float*)alloc((size_t)B_ * H_ * S_ * 4);
  float* beta = (float*)alloc((size_t)B_ * H_ * S_ * 4);
  float* attn = (float*)xqkv;    // alias (xqkv dead after prep)
  unsigned short* normed = rqk;  // alias (rqk dead after prep)
  // WY pre-pass outputs alias xb (dead after fl_gemm / gemms): 8+4+2 = 14MB
  char* xbc = (char*)xb;
  float* Aw = (float*)xbc;                                     // 8MB
  unsigned short* Mw = (unsigned short*)(xbc + 8u * 1024 * 1024);  // 4MB
  float* Gw = (float*)(xbc + 12u * 1024 * 1024);               // 2MB

  if (used > ws_size) return;

  cast_bf16_kernel<<<2048, 256, 0, stream>>>(x, xb, M_ * D_ / 4);

  dim3 tb(32, 8);
  transpose_w_kernel<<<dim3(32, 32), tb, 0, stream>>>(Wq, wqkv_t, 1024, 1024);
  transpose_w_kernel<<<dim3(32, 32), tb, 0, stream>>>(
      Wk, wqkv_t + (size_t)1024 * 1024, 1024, 1024);
  transpose_w_kernel<<<dim3(32, 32), tb, 0, stream>>>(
      Wv, wqkv_t + (size_t)2048 * 1024, 1024, 1024);
  transpose_w_kernel<<<dim3(24, 32), tb, 0, stream>>>(
      (const float*)d_in[12], wr_t, 1024, 768);
  transpose_w_kernel<<<dim3(24, 32), tb, 0, stream>>>(
      (const float*)d_in[13], wr_t + (size_t)768 * 1024, 1024, 768);
  transpose_w_kernel<<<dim3(32, 32), tb, 0, stream>>>(Wo, wo_t, 1024, 1024);
  pack_wfl_kernel<<<128, 256, 0, stream>>>(Wf, Wl, wfl);

  gemm_bt_kernel<true><<<64 * 24, 256, 0, stream>>>(xb, wqkv_t, xqkv, M_, 3072, 1024);
  gemm_bt_kernel<true><<<64 * 12, 256, 0, stream>>>(xb, wr_t, rqk, M_, 1536, 1024);

  fl_gemm_kernel<<<64, 256, 0, stream>>>(xb, wfl, bfv, blv, alpha, beta);

  prep_kernel<<<M_, 256, 0, stream>>>(xqkv, rqk, conv_q, conv_k, conv_v, gs,
                                      qn_w, kn_w, qt, kt, vc);

  wy_pre_kernel<<<32 * 256, 64, 0, stream>>>(qt, kt, alpha, beta, Aw, Mw, Gw);

  scan_wy_kernel<<<128, 256, 0, stream>>>(qt, kt, vc, Aw, Mw, Gw, attn);

  rmsnorm_out_kernel<<<M_, 256, 0, stream>>>(attn, on_w, normed);

  gemm_bt_kernel<false><<<64 * 8, 256, 0, stream>>>(normed, wo_t, (float*)d_out,
                                                    M_, 1024, 1024);
}